// Round 7
// baseline (553.606 us; speedup 1.0000x reference)
//
#include <hip/hip_runtime.h>

#define N_NODES 100000
#define N_PAD   100096      // 782 * 128
#define N_EDGES 1600000
#define NEG_SLOPE 0.2f
#define BN_EPS 1e-5f

typedef __attribute__((ext_vector_type(8))) short short8;
typedef __attribute__((ext_vector_type(4))) float floatx4;
typedef __attribute__((ext_vector_type(4))) float fx4;       // for nt builtins
typedef __attribute__((ext_vector_type(2))) unsigned int ux2;

// ---------------- workspace layout (bytes) ----------------
static const size_t OFF_AB   = 0;            // feats bf16 fragment-ordered [N_PAD,128]
static const size_t OFF_BB   = 25624576;     // weights bf16 fragment-ordered [512,128]
static const size_t OFF_H    = 25755648;     // h bf16 [N,256]
static const size_t OFF_RES  = 76955648;     // res+bias bf16 [N,256]
static const size_t OFF_EL   = 128155648;    // el [N,4] f32
static const size_t OFF_ER   = 129755648;    // er [N,4] f32
static const size_t OFF_DEG  = 131355648;    // deg [N] i32
static const size_t OFF_RS   = 131755648;    // row_start [N+1] i32
static const size_t OFF_CUR  = 132155664;    // cursor [N] i32
static const size_t OFF_ESRC = 132555664;    // edge src ids [E] i32
static const size_t OFF_BS   = 138955664;    // block sums [128] i32
static const size_t OFF_BN   = 138956176;    // bn accum [128] f32
// total ~139 MB

__device__ __forceinline__ unsigned short f2bf(float x) {
  unsigned int u = __float_as_uint(x);
  unsigned int r = (u + 0x7fffu + ((u >> 16) & 1u)) >> 16;   // RNE
  return (unsigned short)r;
}
__device__ __forceinline__ float bf2f(unsigned short u) {
  return __uint_as_float(((unsigned int)u) << 16);
}
__device__ __forceinline__ float bf_lo(unsigned int u) {
  return __uint_as_float(u << 16);
}
__device__ __forceinline__ float bf_hi(unsigned int u) {
  return __uint_as_float(u & 0xffff0000u);
}
__device__ __forceinline__ unsigned int pack2bf(float a, float b) {
  return (unsigned int)f2bf(a) | ((unsigned int)f2bf(b) << 16);
}

// ---------------- fused pre-pass: cvt_a | edge count | cvt_w ----------------
__global__ __launch_bounds__(256) void k_pre(
    const float* __restrict__ feats, const float* __restrict__ fc_w,
    const float* __restrict__ res_w, const int* __restrict__ dst,
    unsigned short* __restrict__ Ab, unsigned short* __restrict__ Bb,
    int* __restrict__ deg)
{
  const int b = blockIdx.x;
  if (b < 6256) {                                // ---- cvt_a (feats read once: nt)
    int c = b * 256 + threadIdx.x;
    int r = c >> 4, j = c & 15;
    unsigned short v[8];
    if (r < N_NODES) {
      const float* p = feats + (size_t)r * 128 + j * 8;
      fx4 a  = __builtin_nontemporal_load((const fx4*)p);
      fx4 bb = __builtin_nontemporal_load((const fx4*)(p + 4));
      v[0]=f2bf(a[0]); v[1]=f2bf(a[1]); v[2]=f2bf(a[2]); v[3]=f2bf(a[3]);
      v[4]=f2bf(bb[0]); v[5]=f2bf(bb[1]); v[6]=f2bf(bb[2]); v[7]=f2bf(bb[3]);
    } else {
      for (int i = 0; i < 8; i++) v[i] = 0;
    }
    size_t idx = (size_t)(r >> 7) * 2048 + ((r >> 4) & 7) * 256 + (j >> 2) * 64
               + (r & 15) + 16 * (j & 3);
    *(short8*)(Ab + idx * 8) = *(short8*)v;
  } else if (b < 12506) {                        // ---- count degrees
    int e = (b - 6256) * 256 + threadIdx.x;
    if (e < N_EDGES) atomicAdd(&deg[__builtin_nontemporal_load(dst + e)], 1);
  } else {                                       // ---- cvt_w
    int c = (b - 12506) * 256 + threadIdx.x;
    int n = c >> 4, j = c & 15;
    const float* W = (n < 256) ? (fc_w + (size_t)n * 128) : (res_w + (size_t)(n - 256) * 128);
    const float* p = W + j * 8;
    float4 a = *(const float4*)p, bb = *(const float4*)(p + 4);
    unsigned short v[8];
    v[0]=f2bf(a.x); v[1]=f2bf(a.y); v[2]=f2bf(a.z); v[3]=f2bf(a.w);
    v[4]=f2bf(bb.x); v[5]=f2bf(bb.y); v[6]=f2bf(bb.z); v[7]=f2bf(bb.w);
    size_t idx = (size_t)(n >> 7) * 2048 + ((n >> 4) & 7) * 256 + (j >> 2) * 64
               + (n & 15) + 16 * (j & 3);
    *(short8*)(Bb + idx * 8) = *(short8*)v;
  }
}

// ---------------- MFMA projection + fused el/er -----------------------------
// OPERAND-SWAPPED: acc[mt][nt] = mfma(b[nt], a[mt]) so C "cols" = node rows.
// Lane (q=L>>4, cn=L&15) holds node row mt*16+cn, cols nt*16 + q*4 + reg
// -> 4 consecutive cols per fragment: one packed 8 B store per fragment.
__global__ __launch_bounds__(256) void k_mm(
    const unsigned short* __restrict__ Ab, const unsigned short* __restrict__ Bb,
    const float* __restrict__ bias, const float* __restrict__ attn_l,
    const float* __restrict__ attn_r,
    unsigned short* __restrict__ hbuf, unsigned short* __restrict__ resbuf,
    float* __restrict__ el, float* __restrict__ er)
{
  __shared__ unsigned short sA[16384];  // 32 KB, fragment-ordered A block
  const int tid = threadIdx.x;
  const int w = tid >> 6, L = tid & 63;
  const int blk = blockIdx.x, nb = blockIdx.y;

  {
    const unsigned short* ga = Ab + (size_t)blk * 16384;
    #pragma unroll
    for (int i = 0; i < 8; i++) {
      int off = (i * 256 + w * 64) * 8;
      __builtin_amdgcn_global_load_lds(
          (const __attribute__((address_space(1))) unsigned int*)(ga + off + L * 8),
          (__attribute__((address_space(3))) unsigned int*)(sA + off),
          16, 0, 0);
    }
  }
  const int mh = w & 1, nh = w >> 1;
  floatx4 acc[4][4] = {};
  __syncthreads();

  const unsigned short* gb = Bb + ((size_t)nb * 2048 + nh * 4 * 256) * 8 + L * 8;
  #pragma unroll
  for (int s = 0; s < 4; s++) {
    short8 a[4], b[4];
    #pragma unroll
    for (int t = 0; t < 4; t++)
      a[t] = *(const short8*)(sA + ((mh * 4 + t) * 256 + s * 64 + L) * 8);
    #pragma unroll
    for (int t = 0; t < 4; t++)
      b[t] = *(const short8*)(gb + ((size_t)t * 256 + s * 64) * 8);
    #pragma unroll
    for (int mt = 0; mt < 4; mt++)
      #pragma unroll
      for (int nt = 0; nt < 4; nt++)
        acc[mt][nt] = __builtin_amdgcn_mfma_f32_16x16x32_bf16(b[nt], a[mt], acc[mt][nt], 0, 0, 0);
  }

  const int q = L >> 4, cn = L & 15;
  const int r0 = blk * 128 + mh * 64;
  if (nb < 2) {
    const int head = nb * 2 + nh;
    const int col0 = nb * 128 + nh * 64;
    float4 alv[4], arv[4];
    #pragma unroll
    for (int nt = 0; nt < 4; nt++) {
      alv[nt] = *(const float4*)(attn_l + head * 64 + nt * 16 + q * 4);
      arv[nt] = *(const float4*)(attn_r + head * 64 + nt * 16 + q * 4);
    }
    #pragma unroll
    for (int mt = 0; mt < 4; mt++) {
      const int row = r0 + mt * 16 + cn;
      float pl = 0.f, pr = 0.f;
      #pragma unroll
      for (int nt = 0; nt < 4; nt++) {
        pl = fmaf(acc[mt][nt][0], alv[nt].x, pl); pr = fmaf(acc[mt][nt][0], arv[nt].x, pr);
        pl = fmaf(acc[mt][nt][1], alv[nt].y, pl); pr = fmaf(acc[mt][nt][1], arv[nt].y, pr);
        pl = fmaf(acc[mt][nt][2], alv[nt].z, pl); pr = fmaf(acc[mt][nt][2], arv[nt].z, pr);
        pl = fmaf(acc[mt][nt][3], alv[nt].w, pl); pr = fmaf(acc[mt][nt][3], arv[nt].w, pr);
      }
      // reduce over q groups (lanes cn, cn+16, cn+32, cn+48)
      pl += __shfl_xor(pl, 16, 64);  pl += __shfl_xor(pl, 32, 64);
      pr += __shfl_xor(pr, 16, 64);  pr += __shfl_xor(pr, 32, 64);
      if (row < N_NODES) {
        #pragma unroll
        for (int nt = 0; nt < 4; nt++) {
          ux2 pk;
          pk[0] = pack2bf(acc[mt][nt][0], acc[mt][nt][1]);
          pk[1] = pack2bf(acc[mt][nt][2], acc[mt][nt][3]);
          *(ux2*)(hbuf + (size_t)row * 256 + col0 + nt * 16 + q * 4) = pk;
        }
        if (q == 0) {
          el[row * 4 + head] = pl;
          er[row * 4 + head] = pr;
        }
      }
    }
  } else {
    const int rc0 = (nb - 2) * 128 + nh * 64;
    float4 bv[4];
    #pragma unroll
    for (int nt = 0; nt < 4; nt++)
      bv[nt] = *(const float4*)(bias + rc0 + nt * 16 + q * 4);
    #pragma unroll
    for (int mt = 0; mt < 4; mt++) {
      const int row = r0 + mt * 16 + cn;
      if (row < N_NODES) {
        #pragma unroll
        for (int nt = 0; nt < 4; nt++) {
          ux2 pk;
          pk[0] = pack2bf(acc[mt][nt][0] + bv[nt].x, acc[mt][nt][1] + bv[nt].y);
          pk[1] = pack2bf(acc[mt][nt][2] + bv[nt].z, acc[mt][nt][3] + bv[nt].w);
          __builtin_nontemporal_store(pk, (ux2*)(resbuf + (size_t)row * 256 + rc0 + nt * 16 + q * 4));
        }
      }
    }
  }
}

// ---------------- CSR build ----------------
__global__ __launch_bounds__(256) void k_scan1(const int* __restrict__ deg,
                                               int* __restrict__ rs, int* __restrict__ bsums)
{
  __shared__ int tmp[256];
  const int t = threadIdx.x;
  const int base = blockIdx.x * 1024 + t * 4;
  int v0 = 0, v1 = 0, v2 = 0, v3 = 0;
  if (base + 0 < N_NODES) v0 = deg[base + 0];
  if (base + 1 < N_NODES) v1 = deg[base + 1];
  if (base + 2 < N_NODES) v2 = deg[base + 2];
  if (base + 3 < N_NODES) v3 = deg[base + 3];
  const int tsum = v0 + v1 + v2 + v3;
  tmp[t] = tsum;
  __syncthreads();
  for (int o = 1; o < 256; o <<= 1) {
    int x = (t >= o) ? tmp[t - o] : 0;
    __syncthreads();
    tmp[t] += x;
    __syncthreads();
  }
  const int excl = tmp[t] - tsum;
  if (base + 0 < N_NODES) rs[base + 0] = excl;
  if (base + 1 < N_NODES) rs[base + 1] = excl + v0;
  if (base + 2 < N_NODES) rs[base + 2] = excl + v0 + v1;
  if (base + 3 < N_NODES) rs[base + 3] = excl + v0 + v1 + v2;
  if (t == 255) bsums[blockIdx.x] = tmp[t];
}

__global__ __launch_bounds__(256) void k_scan3(int* __restrict__ rs,
                                               const int* __restrict__ bsums,
                                               int* __restrict__ cursor)
{
  __shared__ int sb[128];
  const int t = threadIdx.x;
  int raw = 0;
  if (t < 128) { raw = (t < 98) ? bsums[t] : 0; sb[t] = raw; }
  __syncthreads();
  for (int o = 1; o < 128; o <<= 1) {
    int x = (t >= o && t < 128) ? sb[t - o] : 0;
    __syncthreads();
    if (t < 128) sb[t] += x;
    __syncthreads();
  }
  if (t < 128) sb[t] -= raw;
  __syncthreads();
  const int i = blockIdx.x * 256 + t;
  if (i < N_NODES) {
    int v = rs[i] + sb[i >> 10];
    rs[i] = v;
    cursor[i] = v;
  } else if (i == N_NODES) {
    rs[N_NODES] = N_EDGES;
  }
}

__global__ __launch_bounds__(256) void k_scatter(const int* __restrict__ src,
                                                 const int* __restrict__ dst,
                                                 int* __restrict__ cursor,
                                                 int* __restrict__ esrc)
{
  int e = blockIdx.x * 256 + threadIdx.x;
  if (e >= N_EDGES) return;
  int s = __builtin_nontemporal_load(src + e);
  int d = __builtin_nontemporal_load(dst + e);
  int pos = atomicAdd(&cursor[d], 1);
  esrc[pos] = s;
}

// ---------------- fused softmax + aggregation + residual/ELU/head-mean ------
// one wave per dst node; 8-deep edge batching (R3-proven); streaming data
// (resbuf, out) non-temporal so the hot random hbuf stays cached.
__global__ __launch_bounds__(256) void k_agg(
    const unsigned short* __restrict__ hbuf, const unsigned short* __restrict__ resbuf,
    const float* __restrict__ el, const float* __restrict__ er,
    const int* __restrict__ rs, const int* __restrict__ esrc,
    float* __restrict__ out, float* __restrict__ bn)
{
  const int lane = threadIdx.x & 63;
  const int head = lane >> 4;
  const int waveG = blockIdx.x * 4 + (threadIdx.x >> 6);
  const int nW = gridDim.x * 4;
  float4 s4 = make_float4(0.f, 0.f, 0.f, 0.f);
  float4 q4 = make_float4(0.f, 0.f, 0.f, 0.f);
  for (int n = waveG; n < N_NODES; n += nW) {
    const int nu = __builtin_amdgcn_readfirstlane(n);
    const int p0 = __builtin_amdgcn_readfirstlane(rs[nu]);
    const int p1 = __builtin_amdgcn_readfirstlane(rs[nu + 1]);
    const float ern = er[nu * 4 + head];
    float4 acc = make_float4(0.f, 0.f, 0.f, 0.f);
    float ssum = 0.f;
    int p = p0;
    for (; p + 8 <= p1; p += 8) {            // 8 edges in flight
      int sn[8];
      #pragma unroll
      for (int i = 0; i < 8; i++) sn[i] = esrc[p + i];
      float ev[8];
      #pragma unroll
      for (int i = 0; i < 8; i++) ev[i] = el[sn[i] * 4 + head];
      ushort4 hv[8];
      #pragma unroll
      for (int i = 0; i < 8; i++)
        hv[i] = *(const ushort4*)(hbuf + (size_t)sn[i] * 256 + lane * 4);
      #pragma unroll
      for (int i = 0; i < 8; i++) {
        float e = ev[i] + ern;
        e = (e > 0.f) ? e : NEG_SLOPE * e;
        const float wgt = __expf(e);
        ssum += wgt;
        acc.x = fmaf(wgt, bf2f(hv[i].x), acc.x);
        acc.y = fmaf(wgt, bf2f(hv[i].y), acc.y);
        acc.z = fmaf(wgt, bf2f(hv[i].z), acc.z);
        acc.w = fmaf(wgt, bf2f(hv[i].w), acc.w);
      }
    }
    for (; p + 4 <= p1; p += 4) {            // 4-wide step
      int sn[4];
      #pragma unroll
      for (int i = 0; i < 4; i++) sn[i] = esrc[p + i];
      float ev[4];
      #pragma unroll
      for (int i = 0; i < 4; i++) ev[i] = el[sn[i] * 4 + head];
      ushort4 hv[4];
      #pragma unroll
      for (int i = 0; i < 4; i++)
        hv[i] = *(const ushort4*)(hbuf + (size_t)sn[i] * 256 + lane * 4);
      #pragma unroll
      for (int i = 0; i < 4; i++) {
        float e = ev[i] + ern;
        e = (e > 0.f) ? e : NEG_SLOPE * e;
        const float wgt = __expf(e);
        ssum += wgt;
        acc.x = fmaf(wgt, bf2f(hv[i].x), acc.x);
        acc.y = fmaf(wgt, bf2f(hv[i].y), acc.y);
        acc.z = fmaf(wgt, bf2f(hv[i].z), acc.z);
        acc.w = fmaf(wgt, bf2f(hv[i].w), acc.w);
      }
    }
    for (; p < p1; p++) {                    // tail
      int sn = esrc[p];
      float e = el[sn * 4 + head] + ern;
      e = (e > 0.f) ? e : NEG_SLOPE * e;
      const float wgt = __expf(e);
      ssum += wgt;
      const ushort4 hv4 = *(const ushort4*)(hbuf + (size_t)sn * 256 + lane * 4);
      acc.x = fmaf(wgt, bf2f(hv4.x), acc.x);
      acc.y = fmaf(wgt, bf2f(hv4.y), acc.y);
      acc.z = fmaf(wgt, bf2f(hv4.z), acc.z);
      acc.w = fmaf(wgt, bf2f(hv4.w), acc.w);
    }
    const float inv = (p1 > p0) ? (1.0f / ssum) : 0.f;
    const ux2 rv = __builtin_nontemporal_load((const ux2*)(resbuf + (size_t)nu * 256 + lane * 4));
    float4 v;
    v.x = fmaf(acc.x, inv, bf_lo(rv[0]));
    v.y = fmaf(acc.y, inv, bf_hi(rv[0]));
    v.z = fmaf(acc.z, inv, bf_lo(rv[1]));
    v.w = fmaf(acc.w, inv, bf_hi(rv[1]));
    v.x = (v.x > 0.f) ? v.x : (__expf(v.x) - 1.f);
    v.y = (v.y > 0.f) ? v.y : (__expf(v.y) - 1.f);
    v.z = (v.z > 0.f) ? v.z : (__expf(v.z) - 1.f);
    v.w = (v.w > 0.f) ? v.w : (__expf(v.w) - 1.f);
    v.x += __shfl_xor(v.x, 16, 64);  v.x += __shfl_xor(v.x, 32, 64);
    v.y += __shfl_xor(v.y, 16, 64);  v.y += __shfl_xor(v.y, 32, 64);
    v.z += __shfl_xor(v.z, 16, 64);  v.z += __shfl_xor(v.z, 32, 64);
    v.w += __shfl_xor(v.w, 16, 64);  v.w += __shfl_xor(v.w, 32, 64);
    if (lane < 16) {
      v.x *= 0.25f; v.y *= 0.25f; v.z *= 0.25f; v.w *= 0.25f;
      fx4 vv; vv[0] = v.x; vv[1] = v.y; vv[2] = v.z; vv[3] = v.w;
      __builtin_nontemporal_store(vv, (fx4*)(out + (size_t)nu * 64 + lane * 4));
      s4.x += v.x; s4.y += v.y; s4.z += v.z; s4.w += v.w;
      q4.x += v.x * v.x; q4.y += v.y * v.y; q4.z += v.z * v.z; q4.w += v.w * v.w;
    }
  }
  __shared__ float lsum[64], lsq[64];
  if (threadIdx.x < 64) { lsum[threadIdx.x] = 0.f; lsq[threadIdx.x] = 0.f; }
  __syncthreads();
  if (lane < 16) {
    atomicAdd(&lsum[lane * 4 + 0], s4.x);  atomicAdd(&lsq[lane * 4 + 0], q4.x);
    atomicAdd(&lsum[lane * 4 + 1], s4.y);  atomicAdd(&lsq[lane * 4 + 1], q4.y);
    atomicAdd(&lsum[lane * 4 + 2], s4.z);  atomicAdd(&lsq[lane * 4 + 2], q4.z);
    atomicAdd(&lsum[lane * 4 + 3], s4.w);  atomicAdd(&lsq[lane * 4 + 3], q4.w);
  }
  __syncthreads();
  if (threadIdx.x < 64) {
    atomicAdd(&bn[threadIdx.x], lsum[threadIdx.x]);
    atomicAdd(&bn[64 + threadIdx.x], lsq[threadIdx.x]);
  }
}

// ---------------- batchnorm (stats folded in) ----------------
__global__ __launch_bounds__(256) void k_bn_apply(float* __restrict__ out,
                                                  const float* __restrict__ bn,
                                                  const float* __restrict__ gamma,
                                                  const float* __restrict__ beta)
{
  __shared__ float sc[64], sh[64];
  const int t = threadIdx.x;
  if (t < 64) {
    float mean = bn[t] * (1.0f / N_NODES);
    float var = bn[64 + t] * (1.0f / N_NODES) - mean * mean;
    float s = gamma[t] * rsqrtf(var + BN_EPS);
    sc[t] = s;
    sh[t] = beta[t] - mean * s;
  }
  __syncthreads();
  const int i = blockIdx.x * 256 + t;
  if (i >= N_NODES * 16) return;
  const int d0 = (i & 15) * 4;
  float4 v = *(float4*)(out + (size_t)i * 4);
  v.x = fmaf(v.x, sc[d0 + 0], sh[d0 + 0]);
  v.y = fmaf(v.y, sc[d0 + 1], sh[d0 + 1]);
  v.z = fmaf(v.z, sc[d0 + 2], sh[d0 + 2]);
  v.w = fmaf(v.w, sc[d0 + 3], sh[d0 + 3]);
  *(float4*)(out + (size_t)i * 4) = v;
}

extern "C" void kernel_launch(void* const* d_in, const int* in_sizes, int n_in,
                              void* d_out, int out_size, void* d_ws, size_t ws_size,
                              hipStream_t stream)
{
  const float* feats  = (const float*)d_in[0];
  const int*   src    = (const int*)d_in[1];
  const int*   dst    = (const int*)d_in[2];
  const float* fc_w   = (const float*)d_in[3];
  const float* attn_l = (const float*)d_in[4];
  const float* attn_r = (const float*)d_in[5];
  const float* res_w  = (const float*)d_in[6];
  const float* bias   = (const float*)d_in[7];
  const float* gamma  = (const float*)d_in[8];
  const float* beta   = (const float*)d_in[9];

  char* ws = (char*)d_ws;
  unsigned short* Ab     = (unsigned short*)(ws + OFF_AB);
  unsigned short* Bb     = (unsigned short*)(ws + OFF_BB);
  unsigned short* hbuf   = (unsigned short*)(ws + OFF_H);
  unsigned short* resbuf = (unsigned short*)(ws + OFF_RES);
  float* elb    = (float*)(ws + OFF_EL);
  float* erb    = (float*)(ws + OFF_ER);
  int*   deg    = (int*)(ws + OFF_DEG);
  int*   rsb    = (int*)(ws + OFF_RS);
  int*   curb   = (int*)(ws + OFF_CUR);
  int*   esrc   = (int*)(ws + OFF_ESRC);
  int*   bsums  = (int*)(ws + OFF_BS);
  float* bnb    = (float*)(ws + OFF_BN);
  float* outp   = (float*)d_out;

  hipMemsetAsync(deg, 0, N_NODES * sizeof(int), stream);
  hipMemsetAsync(bnb, 0, 128 * sizeof(float), stream);

  k_pre<<<12538, 256, 0, stream>>>(feats, fc_w, res_w, dst, Ab, Bb, deg);
  k_mm<<<dim3(782, 4), 256, 0, stream>>>(Ab, Bb, bias, attn_l, attn_r,
                                         hbuf, resbuf, elb, erb);
  k_scan1<<<98, 256, 0, stream>>>(deg, rsb, bsums);
  k_scan3<<<391, 256, 0, stream>>>(rsb, bsums, curb);
  k_scatter<<<6250, 256, 0, stream>>>(src, dst, curb, esrc);
  k_agg<<<2048, 256, 0, stream>>>(hbuf, resbuf, elb, erb, rsb, esrc, outp, bnb);
  k_bn_apply<<<6250, 256, 0, stream>>>(outp, bnb, gamma, beta);
}